// Round 9
// baseline (75.824 us; speedup 1.0000x reference)
//
#include <hip/hip_runtime.h>
#include <hip/hip_bf16.h>
#include <math.h>

#define BATCH   2048
#define NINTRS  256
#define VALID   128
#define NATOMS  256
#define DDIM    28   // 3*9+1

typedef float  f32x4  __attribute__((ext_vector_type(4)));
typedef short  bf16x8 __attribute__((ext_vector_type(8)));

__device__ __forceinline__ unsigned short f32_to_bf16(float f) {
    unsigned int u = __float_as_uint(f);
    u = (u + 0x7FFFu + ((u >> 16) & 1u)) >> 16;   // RNE
    return (unsigned short)u;
}

// ---------------------------------------------------------------------------
// Pre-pass 1: ab[d][a] = 16B chunk {bf16 atoms[a][d][c], c=0..7}. 112 KB.
// ---------------------------------------------------------------------------
__global__ __launch_bounds__(256)
void build_atomsB(const float* __restrict__ atoms, unsigned short* __restrict__ ab)
{
    const int t = blockIdx.x * 256 + threadIdx.x;   // 0..7167
    const int d = t >> 8;
    const int a = t & 255;
    const float* src = atoms + ((size_t)a * DDIM + d) * 8;
    f32x4 v0 = *(const f32x4*)(src);
    f32x4 v1 = *(const f32x4*)(src + 4);
    bf16x8 o;
    #pragma unroll
    for (int j = 0; j < 4; ++j) {
        o[j]   = (short)f32_to_bf16(v0[j]);
        o[j+4] = (short)f32_to_bf16(v1[j]);
    }
    *(bf16x8*)(ab + (size_t)t * 8) = o;
}

// ---------------------------------------------------------------------------
// Pre-pass 2: SH-contract the dictionary for ALL rays. Block b handles rays
// b*8..b*8+7; thread owns atom a = tid; ab loaded ONCE (coalesced) and reused
// for 8 rays. Output bst[ray] = the 16 KB XOR-swizzled LDS image the main
// kernel DMAs verbatim (byte = col*512 + a*2, XOR (col&7)<<4).
// Replaces 2048x112KB of per-block ab traffic with 256x112KB.
// ---------------------------------------------------------------------------
__global__ __launch_bounds__(256)
void build_bs_all(const unsigned short* __restrict__ ab,
                  const float* __restrict__ raysd,
                  unsigned short* __restrict__ bst)
{
    const int a = threadIdx.x;
    const int rbase = blockIdx.x * 8;

    bf16x8 abv[28];
    #pragma unroll
    for (int d = 0; d < 28; ++d)
        abv[d] = *(const bf16x8*)(ab + ((size_t)(d * 256 + a)) * 8);

    for (int r = 0; r < 8; ++r) {
        const int ray = rbase + r;
        const float rdx = raysd[ray*3+0], rdy = raysd[ray*3+1], rdz = raysd[ray*3+2];
        const float rn = rsqrtf(rdx*rdx + rdy*rdy + rdz*rdz);
        const float x = rdx*rn, y = rdy*rn, z = rdz*rn;
        float sh[9];
        sh[0] = 0.28209479177387814f;
        sh[1] = -0.4886025119029199f * y;
        sh[2] =  0.4886025119029199f * z;
        sh[3] = -0.4886025119029199f * x;
        sh[4] =  1.0925484305920792f * x * y;
        sh[5] = -1.0925484305920792f * y * z;
        sh[6] =  0.31539156525252005f * (2.0f*z*z - x*x - y*y);
        sh[7] = -1.0925484305920792f * x * z;
        sh[8] =  0.5462742152960396f * (x - y) * (x + y);

        float accB[3][8];
        #pragma unroll
        for (int k = 0; k < 3; ++k)
            #pragma unroll
            for (int c = 0; c < 8; ++c) accB[k][c] = 0.0f;
        #pragma unroll
        for (int d = 0; d < 27; ++d) {
            const int kp = d / 9, j = d - kp * 9;
            const float s = sh[j];
            const unsigned int* u = (const unsigned int*)&abv[d];
            #pragma unroll
            for (int i = 0; i < 4; ++i) {
                const float flo = __uint_as_float(u[i] << 16);
                const float fhi = __uint_as_float(u[i] & 0xffff0000u);
                accB[kp][2*i]   = fmaf(s, flo, accB[kp][2*i]);
                accB[kp][2*i+1] = fmaf(s, fhi, accB[kp][2*i+1]);
            }
        }

        char* ob = (char*)bst + (size_t)ray * 16384;
        #pragma unroll
        for (int kp = 0; kp < 3; ++kp)
            #pragma unroll
            for (int c = 0; c < 8; ++c) {
                const int col = kp*8 + c;
                unsigned byte = ((unsigned)col << 9) + ((unsigned)a << 1);
                byte ^= (unsigned)((col & 7) << 4);
                *(unsigned short*)(ob + byte) = f32_to_bf16(accB[kp][c]);
            }
        const unsigned short* sv = (const unsigned short*)&abv[27];
        #pragma unroll
        for (int c = 0; c < 8; ++c) {
            const int col = 24 + c;
            unsigned byte = ((unsigned)col << 9) + ((unsigned)a << 1);
            byte ^= (unsigned)((col & 7) << 4);
            *(unsigned short*)(ob + byte) = sv[c];
        }
    }
}

// ---------------------------------------------------------------------------
// Main: one block per ray. Bs[ray] (16 KB, pre-swizzled) arrives via 4x16B
// global_load_lds per thread; A-operands prefetched straight from global q
// into registers via inline-asm global_load_dwordx4, depth-4, counted vmcnt
// + sched_barrier(0) (rule #18). No phase B, no SH in this kernel.
// ---------------------------------------------------------------------------
__global__ __launch_bounds__(256, 4)
void shdict_fused(const float* __restrict__ q,      // [BATCH*VALID][256]
                  const unsigned short* __restrict__ bst, // [2048][16KB images]
                  const float* __restrict__ ipts,   // [BATCH*VALID][3]
                  const float* __restrict__ intr,   // [BATCH][257]
                  const float* __restrict__ raysd,  // [BATCH][3]
                  float* __restrict__ out_rgb,      // [BATCH][3]
                  float* __restrict__ out_alpha,    // [BATCH][256]
                  float* __restrict__ out_depth)    // [BATCH]
{
    __shared__ char  bs[32 * 256 * 2];      // 16 KB Bs[col][a] bf16, XOR-swizzled
    __shared__ float w_lds[VALID][9];       // trilinear weights (+1 pad)
    __shared__ float pr_lds[VALID][5];      // rgb0,rgb1,rgb2,sigma (+1 pad)

    const int ray  = blockIdx.x;
    const int tid  = threadIdx.x;
    const int lane = tid & 63;
    const int wav  = tid >> 6;

    // ---- compiler-managed input loads; consumed, then drained ----
    const float rdx = raysd[ray*3+0], rdy = raysd[ray*3+1], rdz = raysd[ray*3+2];
    const float ss  = rdx*rdx + rdy*rdy + rdz*rdz;
    if (tid < VALID) {
        const int n = ray * VALID + tid;
        const float px = ipts[n*3+0]*128.0f + 1e-5f;
        const float py = ipts[n*3+1]*128.0f + 1e-5f;
        const float pz = ipts[n*3+2]*128.0f + 1e-5f;
        const float fx = px - floorf(px);
        const float fy = py - floorf(py);
        const float fz = pz - floorf(pz);
        #pragma unroll
        for (int c = 0; c < 8; ++c) {
            const float wx = (c & 4) ? fx : 1.0f - fx;
            const float wy = (c & 2) ? fy : 1.0f - fy;
            const float wz = (c & 1) ? fz : 1.0f - fz;
            w_lds[tid][c] = wx * wy * wz;
        }
    }
    // all compiler VMEM consumed -> drain so asm vmcnt counting is exact
    asm volatile("s_waitcnt vmcnt(0)" ::: "memory");

    // ---- issue Bs DMA (4 x 16B/thread, identity map: image pre-swizzled) ----
    {
        const char* gbs = (const char*)bst + (size_t)ray * 16384
                        + (size_t)wav * 1024 + (size_t)lane * 16;
        char* lbs = (char*)bs + wav * 1024;
        #pragma unroll
        for (int j = 0; j < 4; ++j) {
            __builtin_amdgcn_global_load_lds(
                (const __attribute__((address_space(1))) void*)(gbs + j * 4096),
                (__attribute__((address_space(3))) void*)(lbs + j * 4096),
                16, 0, 0);
        }
    }

    // ---- register prefetch pipeline for A-fragments, depth 4 ----
    const int row  = lane & 15;
    const int kgrp = lane >> 4;
    const float* ga0 = q + (size_t)(ray*VALID + wav*32 + row) * NATOMS + kgrp*8;
    const float* ga1 = ga0 + 16 * NATOMS;

    f32x4 pf[4][4];

#define ISSUE_STEP(s, kk) do {                                                   \
    const float* _p0 = ga0 + (kk)*32;                                            \
    const float* _p1 = ga1 + (kk)*32;                                            \
    asm volatile("global_load_dwordx4 %0, %1, off" : "=v"(pf[s][0]) : "v"(_p0)   : "memory"); \
    asm volatile("global_load_dwordx4 %0, %1, off" : "=v"(pf[s][1]) : "v"(_p0+4) : "memory"); \
    asm volatile("global_load_dwordx4 %0, %1, off" : "=v"(pf[s][2]) : "v"(_p1)   : "memory"); \
    asm volatile("global_load_dwordx4 %0, %1, off" : "=v"(pf[s][3]) : "v"(_p1+4) : "memory"); \
} while (0)

    ISSUE_STEP(0, 0);
    ISSUE_STEP(1, 1);
    ISSUE_STEP(2, 2);
    ISSUE_STEP(3, 3);
    // outstanding: 4 (bs DMA) + 16 (q) = 20, in issue order.

    // w_lds visibility: lgkmcnt drain + raw barrier (no vmcnt drain).
    asm volatile("s_waitcnt lgkmcnt(0)" ::: "memory");
    __builtin_amdgcn_s_barrier();

    // ---- K-loop: 8 steps of K=32, depth-4 register pipeline ----
    f32x4 acc[2][2];
    #pragma unroll
    for (int m = 0; m < 2; ++m)
        #pragma unroll
        for (int n = 0; n < 2; ++n)
            acc[m][n] = (f32x4){0.f, 0.f, 0.f, 0.f};

    #pragma unroll
    for (int ks = 0; ks < 8; ++ks) {
        // wait for step ks's loads (and, at ks=0, the older bs DMA too)
        if (ks <= 4)      asm volatile("s_waitcnt vmcnt(12)" ::: "memory");
        else if (ks == 5) asm volatile("s_waitcnt vmcnt(8)"  ::: "memory");
        else if (ks == 6) asm volatile("s_waitcnt vmcnt(4)"  ::: "memory");
        else              asm volatile("s_waitcnt vmcnt(0)"  ::: "memory");
        __builtin_amdgcn_sched_barrier(0);   // rule #18: pin consumers below

        const int s = ks & 3;
        bf16x8 af0, af1;
        #pragma unroll
        for (int j = 0; j < 4; ++j) {
            af0[j]   = (short)f32_to_bf16(pf[s][0][j]);
            af0[j+4] = (short)f32_to_bf16(pf[s][1][j]);
            af1[j]   = (short)f32_to_bf16(pf[s][2][j]);
            af1[j+4] = (short)f32_to_bf16(pf[s][3][j]);
        }

        if (ks + 4 < 8) ISSUE_STEP(s, ks + 4);

        bf16x8 bfrag[2];
        const int abase = ks*32 + kgrp*8;
        #pragma unroll
        for (int nt = 0; nt < 2; ++nt) {
            const int col = nt*16 + row;
            unsigned byte = ((unsigned)col << 9) + ((unsigned)abase << 1);
            byte ^= (unsigned)((col & 7) << 4);
            bfrag[nt] = *(const bf16x8*)(bs + byte);
        }

        acc[0][0] = __builtin_amdgcn_mfma_f32_16x16x32_bf16(af0, bfrag[0], acc[0][0], 0, 0, 0);
        acc[0][1] = __builtin_amdgcn_mfma_f32_16x16x32_bf16(af0, bfrag[1], acc[0][1], 0, 0, 0);
        acc[1][0] = __builtin_amdgcn_mfma_f32_16x16x32_bf16(af1, bfrag[0], acc[1][0], 0, 0, 0);
        acc[1][1] = __builtin_amdgcn_mfma_f32_16x16x32_bf16(af1, bfrag[1], acc[1][1], 0, 0, 0);
    }
#undef ISSUE_STEP

    // ---- Epilogue: out[pt,kp] = sum_c w[pt,c] * C[pt, kp*8+c] ----
    // D layout: lane holds D[(lane>>4)*4 + r][lane&15]; col = kph*8 + cc.
    const int cc  = lane & 7;
    const int kph = (lane & 15) >> 3;
    #pragma unroll
    for (int m = 0; m < 2; ++m) {
        const int ptb = wav*32 + m*16 + kgrp*4;
        #pragma unroll
        for (int nt = 0; nt < 2; ++nt) {
            const int kp = nt*2 + kph;
            #pragma unroll
            for (int r = 0; r < 4; ++r) {
                float t = acc[m][nt][r] * w_lds[ptb + r][cc];
                t += __shfl_xor(t, 1);
                t += __shfl_xor(t, 2);
                t += __shfl_xor(t, 4);
                if (cc == 0) pr_lds[ptb + r][kp] = t;
            }
        }
    }
    __syncthreads();

    // ---- Render scan (wave 0): 2 samples per lane ----
    if (wav == 0) {
        const float rnorm = sqrtf(ss);
        const int i0 = lane * 2;
        const float t0 = intr[ray*257 + i0];
        const float t1 = intr[ray*257 + i0 + 1];
        const float t2 = intr[ray*257 + i0 + 2];
        const float d0 = (t1 - t0) * rnorm;
        const float d1 = (t2 - t1) * rnorm;
        const float s0 = fmaxf(pr_lds[i0][3],     0.0f);
        const float s1 = fmaxf(pr_lds[i0 + 1][3], 0.0f);
        const float a0 = 1.0f - __expf(-s0 * d0);
        const float a1 = 1.0f - __expf(-s1 * d1);
        const float f0 = 1.0f - a0 + 1e-10f;
        const float f1 = 1.0f - a1 + 1e-10f;

        float pprod = f0 * f1;
        #pragma unroll
        for (int off = 1; off < 64; off <<= 1) {
            float v = __shfl_up(pprod, off);
            if (lane >= off) pprod *= v;
        }
        float excl = __shfl_up(pprod, 1);
        if (lane == 0) excl = 1.0f;

        const float tr0 = excl;
        const float tr1 = excl * f0;
        const float al0 = a0 * tr0;
        const float al1 = a1 * tr1;
        const float mid0 = 0.5f * (t0 + t1);
        const float mid1 = 0.5f * (t1 + t2);

        const float r0 = 1.0f / (1.0f + __expf(-pr_lds[i0][0]));
        const float g0 = 1.0f / (1.0f + __expf(-pr_lds[i0][1]));
        const float b0 = 1.0f / (1.0f + __expf(-pr_lds[i0][2]));
        const float r1 = 1.0f / (1.0f + __expf(-pr_lds[i0 + 1][0]));
        const float g1 = 1.0f / (1.0f + __expf(-pr_lds[i0 + 1][1]));
        const float b1 = 1.0f / (1.0f + __expf(-pr_lds[i0 + 1][2]));

        float sum_r = al0*r0 + al1*r1;
        float sum_g = al0*g0 + al1*g1;
        float sum_b = al0*b0 + al1*b1;
        float sum_d = al0*mid0 + al1*mid1;
        float sum_a = al0 + al1;
        #pragma unroll
        for (int off = 1; off < 64; off <<= 1) {
            sum_r += __shfl_xor(sum_r, off);
            sum_g += __shfl_xor(sum_g, off);
            sum_b += __shfl_xor(sum_b, off);
            sum_d += __shfl_xor(sum_d, off);
            sum_a += __shfl_xor(sum_a, off);
        }
        if (lane == 0) {
            const float bkgd = 1.0f - sum_a;
            out_rgb[ray*3 + 0] = sum_r + bkgd;
            out_rgb[ray*3 + 1] = sum_g + bkgd;
            out_rgb[ray*3 + 2] = sum_b + bkgd;
            out_depth[ray]     = sum_d;
        }
        float2 av; av.x = a0; av.y = a1;
        *(float2*)(out_alpha + (size_t)ray*NINTRS + i0) = av;
        float2 zz; zz.x = 0.0f; zz.y = 0.0f;
        *(float2*)(out_alpha + (size_t)ray*NINTRS + VALID + i0) = zz;
    }
}

extern "C" void kernel_launch(void* const* d_in, const int* in_sizes, int n_in,
                              void* d_out, int out_size, void* d_ws, size_t ws_size,
                              hipStream_t stream)
{
    const float* q     = (const float*)d_in[0];
    const float* atoms = (const float*)d_in[1];
    const float* ipts  = (const float*)d_in[2];
    const float* intr  = (const float*)d_in[3];
    const float* raysd = (const float*)d_in[4];
    // d_in[5] (flat_idx) is b*NINTRS+i by construction; derived analytically.

    float* out = (float*)d_out;
    float* out_rgb   = out;
    float* out_alpha = out + BATCH*3;
    float* out_depth = out + BATCH*3 + (size_t)BATCH*NINTRS;

    unsigned short* ab  = (unsigned short*)d_ws;                       // 112 KB
    unsigned short* bst = (unsigned short*)((char*)d_ws + (1 << 20));  // 32 MB

    build_atomsB<<<28, 256, 0, stream>>>(atoms, ab);
    build_bs_all<<<BATCH/8, 256, 0, stream>>>(ab, raysd, bst);
    shdict_fused<<<BATCH, 256, 0, stream>>>(q, bst, ipts, intr, raysd,
                                            out_rgb, out_alpha, out_depth);
}

// Round 10
// 59.229 us; speedup vs baseline: 1.2802x; 1.2802x over previous
//
#include <hip/hip_runtime.h>
#include <hip/hip_bf16.h>
#include <math.h>

#define BATCH   2048
#define NINTRS  256
#define VALID   128
#define NATOMS  256
#define DDIM    28   // 3*9+1

typedef float  f32x4  __attribute__((ext_vector_type(4)));
typedef short  bf16x8 __attribute__((ext_vector_type(8)));

__device__ __forceinline__ unsigned short f32_to_bf16(float f) {
    unsigned int u = __float_as_uint(f);
    u = (u + 0x7FFFu + ((u >> 16) & 1u)) >> 16;   // RNE
    return (unsigned short)u;
}

// ---------------------------------------------------------------------------
// Pre-pass: ab[d][a] = 16B chunk {bf16 atoms[a][d][c], c=0..7}. 112 KB,
// L2-resident; read coalesced by every main block.
// ---------------------------------------------------------------------------
__global__ __launch_bounds__(256)
void build_atomsB(const float* __restrict__ atoms, unsigned short* __restrict__ ab)
{
    const int t = blockIdx.x * 256 + threadIdx.x;   // 0..7167
    const int d = t >> 8;
    const int a = t & 255;
    const float* src = atoms + ((size_t)a * DDIM + d) * 8;
    f32x4 v0 = *(const f32x4*)(src);
    f32x4 v1 = *(const f32x4*)(src + 4);
    bf16x8 o;
    #pragma unroll
    for (int j = 0; j < 4; ++j) {
        o[j]   = (short)f32_to_bf16(v0[j]);
        o[j+4] = (short)f32_to_bf16(v1[j]);
    }
    *(bf16x8*)(ab + (size_t)t * 8) = o;
}

// ---------------------------------------------------------------------------
// Main: one block per TWO rays (ab loaded once, contracted for both).
//   phase B: ab halves -> accB[2 rays][3][8] -> bs0/bs1 (16 KB each, swizzled).
//   K-superloop: 16 steps (8 per ray), depth-4 inline-asm register prefetch
//   of q, uniform counted-vmcnt ladder crossing the ray boundary with no
//   drain. Epilogue(ray0) overlaps ray1's loads; scans run on waves 0 and 1.
// ---------------------------------------------------------------------------
__global__ __launch_bounds__(256, 3)
void shdict_fused(const float* __restrict__ q,      // [BATCH*VALID][256]
                  const unsigned short* __restrict__ ab,  // [28][256] bf16x8
                  const float* __restrict__ ipts,   // [BATCH*VALID][3]
                  const float* __restrict__ intr,   // [BATCH][257]
                  const float* __restrict__ raysd,  // [BATCH][3]
                  float* __restrict__ out_rgb,      // [BATCH][3]
                  float* __restrict__ out_alpha,    // [BATCH][256]
                  float* __restrict__ out_depth)    // [BATCH]
{
    __shared__ char  bs[2][16384];          // per-ray Bs[col][a] bf16, swizzled
    __shared__ float w_lds[2*VALID][9];     // trilinear weights (+1 pad)
    __shared__ float pr_lds[2*VALID][5];    // rgb0,rgb1,rgb2,sigma (+1 pad)

    const int r0   = blockIdx.x * 2;
    const int tid  = threadIdx.x;
    const int lane = tid & 63;
    const int wav  = tid >> 6;

    // ---- compiler-managed input loads ----
    float rd[2][3];
    #pragma unroll
    for (int rr = 0; rr < 2; ++rr)
        #pragma unroll
        for (int j = 0; j < 3; ++j)
            rd[rr][j] = raysd[(r0 + rr)*3 + j];

    {   // phase A: 256 threads cover both rays' 256 points (contiguous in ipts)
        const int n = r0 * VALID + tid;
        const float px = ipts[n*3+0]*128.0f + 1e-5f;
        const float py = ipts[n*3+1]*128.0f + 1e-5f;
        const float pz = ipts[n*3+2]*128.0f + 1e-5f;
        const float fx = px - floorf(px);
        const float fy = py - floorf(py);
        const float fz = pz - floorf(pz);
        #pragma unroll
        for (int c = 0; c < 8; ++c) {
            const float wx = (c & 4) ? fx : 1.0f - fx;
            const float wy = (c & 2) ? fy : 1.0f - fy;
            const float wz = (c & 1) ? fz : 1.0f - fz;
            w_lds[tid][c] = wx * wy * wz;
        }
    }

    // ---- SH basis, both rays ----
    float sh[2][9], ssv[2];
    #pragma unroll
    for (int rr = 0; rr < 2; ++rr) {
        const float rdx = rd[rr][0], rdy = rd[rr][1], rdz = rd[rr][2];
        const float ss = rdx*rdx + rdy*rdy + rdz*rdz;
        ssv[rr] = ss;
        const float rn = rsqrtf(ss);
        const float x = rdx*rn, y = rdy*rn, z = rdz*rn;
        sh[rr][0] = 0.28209479177387814f;
        sh[rr][1] = -0.4886025119029199f * y;
        sh[rr][2] =  0.4886025119029199f * z;
        sh[rr][3] = -0.4886025119029199f * x;
        sh[rr][4] =  1.0925484305920792f * x * y;
        sh[rr][5] = -1.0925484305920792f * y * z;
        sh[rr][6] =  0.31539156525252005f * (2.0f*z*z - x*x - y*y);
        sh[rr][7] = -1.0925484305920792f * x * z;
        sh[rr][8] =  0.5462742152960396f * (x - y) * (x + y);
    }

    // ---- phase B: ab halves -> accB (both rays) -> bs0/bs1 ----
    {
        const int a = tid;
        float accB[2][3][8];
        #pragma unroll
        for (int rr = 0; rr < 2; ++rr)
            #pragma unroll
            for (int k = 0; k < 3; ++k)
                #pragma unroll
                for (int c = 0; c < 8; ++c) accB[rr][k][c] = 0.0f;

        bf16x8 h[14];
        // half 1: d = 0..13
        #pragma unroll
        for (int d = 0; d < 14; ++d)
            h[d] = *(const bf16x8*)(ab + ((size_t)(d * 256 + a)) * 8);
        #pragma unroll
        for (int d = 0; d < 14; ++d) {
            const int kp = d / 9, j = d - kp * 9;
            const unsigned int* u = (const unsigned int*)&h[d];
            #pragma unroll
            for (int i = 0; i < 4; ++i) {
                const float flo = __uint_as_float(u[i] << 16);
                const float fhi = __uint_as_float(u[i] & 0xffff0000u);
                #pragma unroll
                for (int rr = 0; rr < 2; ++rr) {
                    accB[rr][kp][2*i]   = fmaf(sh[rr][j], flo, accB[rr][kp][2*i]);
                    accB[rr][kp][2*i+1] = fmaf(sh[rr][j], fhi, accB[rr][kp][2*i+1]);
                }
            }
        }
        __builtin_amdgcn_sched_barrier(0);   // don't hoist half-2 loads above
        // half 2: d = 14..27 (d=27 sigma raw in h[13])
        #pragma unroll
        for (int d = 0; d < 14; ++d)
            h[d] = *(const bf16x8*)(ab + ((size_t)((d + 14) * 256 + a)) * 8);
        #pragma unroll
        for (int d = 0; d < 13; ++d) {
            const int dd = d + 14;
            const int kp = dd / 9, j = dd - kp * 9;
            const unsigned int* u = (const unsigned int*)&h[d];
            #pragma unroll
            for (int i = 0; i < 4; ++i) {
                const float flo = __uint_as_float(u[i] << 16);
                const float fhi = __uint_as_float(u[i] & 0xffff0000u);
                #pragma unroll
                for (int rr = 0; rr < 2; ++rr) {
                    accB[rr][kp][2*i]   = fmaf(sh[rr][j], flo, accB[rr][kp][2*i]);
                    accB[rr][kp][2*i+1] = fmaf(sh[rr][j], fhi, accB[rr][kp][2*i+1]);
                }
            }
        }
        #pragma unroll
        for (int rr = 0; rr < 2; ++rr) {
            #pragma unroll
            for (int kp = 0; kp < 3; ++kp)
                #pragma unroll
                for (int c = 0; c < 8; ++c) {
                    const int col = kp*8 + c;
                    unsigned byte = ((unsigned)col << 9) + ((unsigned)a << 1);
                    byte ^= (unsigned)((col & 7) << 4);
                    *(unsigned short*)(bs[rr] + byte) = f32_to_bf16(accB[rr][kp][c]);
                }
            const unsigned short* sv = (const unsigned short*)&h[13];
            #pragma unroll
            for (int c = 0; c < 8; ++c) {
                const int col = 24 + c;
                unsigned byte = ((unsigned)col << 9) + ((unsigned)a << 1);
                byte ^= (unsigned)((col & 7) << 4);
                *(unsigned short*)(bs[rr] + byte) = sv[c];
            }
        }
    }

    // ---- A-fragment register prefetch, depth 4, crossing both rays ----
    const int row  = lane & 15;
    const int kgrp = lane >> 4;
    const float* ga[2][2];
    #pragma unroll
    for (int rr = 0; rr < 2; ++rr) {
        ga[rr][0] = q + (size_t)((r0 + rr)*VALID + wav*32 + row) * NATOMS + kgrp*8;
        ga[rr][1] = ga[rr][0] + 16 * NATOMS;
    }

    f32x4 pf[4][4];

#define ISSUE_STEP(s, p0b, p1b, kk) do {                                         \
    const float* _p0 = (p0b) + (kk)*32;                                          \
    const float* _p1 = (p1b) + (kk)*32;                                          \
    asm volatile("global_load_dwordx4 %0, %1, off" : "=v"(pf[s][0]) : "v"(_p0)   : "memory"); \
    asm volatile("global_load_dwordx4 %0, %1, off" : "=v"(pf[s][1]) : "v"(_p0+4) : "memory"); \
    asm volatile("global_load_dwordx4 %0, %1, off" : "=v"(pf[s][2]) : "v"(_p1)   : "memory"); \
    asm volatile("global_load_dwordx4 %0, %1, off" : "=v"(pf[s][3]) : "v"(_p1+4) : "memory"); \
} while (0)

    // all compiler VMEM consumed above -> exact vmcnt counting from here
    asm volatile("s_waitcnt vmcnt(0)" ::: "memory");
    ISSUE_STEP(0, ga[0][0], ga[0][1], 0);
    ISSUE_STEP(1, ga[0][0], ga[0][1], 1);
    ISSUE_STEP(2, ga[0][0], ga[0][1], 2);
    ISSUE_STEP(3, ga[0][0], ga[0][1], 3);

    // bs/w_lds visibility: lgkm drain + raw barrier (no vmcnt drain)
    asm volatile("s_waitcnt lgkmcnt(0)" ::: "memory");
    __builtin_amdgcn_s_barrier();

    f32x4 acc[2][2];
    #pragma unroll
    for (int m = 0; m < 2; ++m)
        #pragma unroll
        for (int n = 0; n < 2; ++n)
            acc[m][n] = (f32x4){0.f, 0.f, 0.f, 0.f};

    const int cc  = lane & 7;
    const int kph = (lane & 15) >> 3;
    auto epilogue = [&](int prbase) {
        #pragma unroll
        for (int m = 0; m < 2; ++m) {
            const int ptb = prbase + wav*32 + m*16 + kgrp*4;
            #pragma unroll
            for (int nt = 0; nt < 2; ++nt) {
                const int kp = nt*2 + kph;
                #pragma unroll
                for (int r = 0; r < 4; ++r) {
                    float t = acc[m][nt][r] * w_lds[ptb + r][cc];
                    t += __shfl_xor(t, 1);
                    t += __shfl_xor(t, 2);
                    t += __shfl_xor(t, 4);
                    if (cc == 0) pr_lds[ptb + r][kp] = t;
                }
            }
        }
    };

    // ---- 16-step K-superloop (8 per ray), seamless vmcnt ladder ----
    #pragma unroll
    for (int gs = 0; gs < 16; ++gs) {
        if (gs <= 12)      asm volatile("s_waitcnt vmcnt(12)" ::: "memory");
        else if (gs == 13) asm volatile("s_waitcnt vmcnt(8)"  ::: "memory");
        else if (gs == 14) asm volatile("s_waitcnt vmcnt(4)"  ::: "memory");
        else               asm volatile("s_waitcnt vmcnt(0)"  ::: "memory");
        __builtin_amdgcn_sched_barrier(0);   // rule #18: pin consumers below

        const int s = gs & 3;
        bf16x8 af0, af1;
        #pragma unroll
        for (int j = 0; j < 4; ++j) {
            af0[j]   = (short)f32_to_bf16(pf[s][0][j]);
            af0[j+4] = (short)f32_to_bf16(pf[s][1][j]);
            af1[j]   = (short)f32_to_bf16(pf[s][2][j]);
            af1[j+4] = (short)f32_to_bf16(pf[s][3][j]);
        }

        if (gs + 4 < 16) {
            const int gi = gs + 4;
            const int ri = gi >> 3;
            ISSUE_STEP(s, ga[ri][0], ga[ri][1], gi & 7);
        }

        bf16x8 bfrag[2];
        const char* bsp = bs[gs >> 3];
        const int abase = (gs & 7)*32 + kgrp*8;
        #pragma unroll
        for (int nt = 0; nt < 2; ++nt) {
            const int col = nt*16 + row;
            unsigned byte = ((unsigned)col << 9) + ((unsigned)abase << 1);
            byte ^= (unsigned)((col & 7) << 4);
            bfrag[nt] = *(const bf16x8*)(bsp + byte);
        }

        acc[0][0] = __builtin_amdgcn_mfma_f32_16x16x32_bf16(af0, bfrag[0], acc[0][0], 0, 0, 0);
        acc[0][1] = __builtin_amdgcn_mfma_f32_16x16x32_bf16(af0, bfrag[1], acc[0][1], 0, 0, 0);
        acc[1][0] = __builtin_amdgcn_mfma_f32_16x16x32_bf16(af1, bfrag[0], acc[1][0], 0, 0, 0);
        acc[1][1] = __builtin_amdgcn_mfma_f32_16x16x32_bf16(af1, bfrag[1], acc[1][1], 0, 0, 0);

        if (gs == 7) {
            // ray0 done: reduce+stash while ray1's loads are in flight
            epilogue(0);
            #pragma unroll
            for (int m = 0; m < 2; ++m)
                #pragma unroll
                for (int n = 0; n < 2; ++n)
                    acc[m][n] = (f32x4){0.f, 0.f, 0.f, 0.f};
        }
    }
#undef ISSUE_STEP
    epilogue(VALID);   // ray1
    __syncthreads();

    // ---- Render scans: wave 0 -> ray0, wave 1 -> ray1 (parallel) ----
    if (wav < 2) {
        const int ray   = r0 + wav;
        const int pbase = wav * VALID;
        const float rnorm = sqrtf(ssv[wav]);
        const int i0 = lane * 2;
        const float t0 = intr[ray*257 + i0];
        const float t1 = intr[ray*257 + i0 + 1];
        const float t2 = intr[ray*257 + i0 + 2];
        const float d0 = (t1 - t0) * rnorm;
        const float d1 = (t2 - t1) * rnorm;
        const float s0 = fmaxf(pr_lds[pbase + i0][3],     0.0f);
        const float s1 = fmaxf(pr_lds[pbase + i0 + 1][3], 0.0f);
        const float a0 = 1.0f - __expf(-s0 * d0);
        const float a1 = 1.0f - __expf(-s1 * d1);
        const float f0 = 1.0f - a0 + 1e-10f;
        const float f1 = 1.0f - a1 + 1e-10f;

        float pprod = f0 * f1;
        #pragma unroll
        for (int off = 1; off < 64; off <<= 1) {
            float v = __shfl_up(pprod, off);
            if (lane >= off) pprod *= v;
        }
        float excl = __shfl_up(pprod, 1);
        if (lane == 0) excl = 1.0f;

        const float tr0 = excl;
        const float tr1 = excl * f0;
        const float al0 = a0 * tr0;
        const float al1 = a1 * tr1;
        const float mid0 = 0.5f * (t0 + t1);
        const float mid1 = 0.5f * (t1 + t2);

        const float r0c = 1.0f / (1.0f + __expf(-pr_lds[pbase + i0][0]));
        const float g0c = 1.0f / (1.0f + __expf(-pr_lds[pbase + i0][1]));
        const float b0c = 1.0f / (1.0f + __expf(-pr_lds[pbase + i0][2]));
        const float r1c = 1.0f / (1.0f + __expf(-pr_lds[pbase + i0 + 1][0]));
        const float g1c = 1.0f / (1.0f + __expf(-pr_lds[pbase + i0 + 1][1]));
        const float b1c = 1.0f / (1.0f + __expf(-pr_lds[pbase + i0 + 1][2]));

        float sum_r = al0*r0c + al1*r1c;
        float sum_g = al0*g0c + al1*g1c;
        float sum_b = al0*b0c + al1*b1c;
        float sum_d = al0*mid0 + al1*mid1;
        float sum_a = al0 + al1;
        #pragma unroll
        for (int off = 1; off < 64; off <<= 1) {
            sum_r += __shfl_xor(sum_r, off);
            sum_g += __shfl_xor(sum_g, off);
            sum_b += __shfl_xor(sum_b, off);
            sum_d += __shfl_xor(sum_d, off);
            sum_a += __shfl_xor(sum_a, off);
        }
        if (lane == 0) {
            const float bkgd = 1.0f - sum_a;
            out_rgb[ray*3 + 0] = sum_r + bkgd;
            out_rgb[ray*3 + 1] = sum_g + bkgd;
            out_rgb[ray*3 + 2] = sum_b + bkgd;
            out_depth[ray]     = sum_d;
        }
        float2 av; av.x = a0; av.y = a1;
        *(float2*)(out_alpha + (size_t)ray*NINTRS + i0) = av;
        float2 zz; zz.x = 0.0f; zz.y = 0.0f;
        *(float2*)(out_alpha + (size_t)ray*NINTRS + VALID + i0) = zz;
    }
}

extern "C" void kernel_launch(void* const* d_in, const int* in_sizes, int n_in,
                              void* d_out, int out_size, void* d_ws, size_t ws_size,
                              hipStream_t stream)
{
    const float* q     = (const float*)d_in[0];
    const float* atoms = (const float*)d_in[1];
    const float* ipts  = (const float*)d_in[2];
    const float* intr  = (const float*)d_in[3];
    const float* raysd = (const float*)d_in[4];
    // d_in[5] (flat_idx) is b*NINTRS+i by construction; derived analytically.

    float* out = (float*)d_out;
    float* out_rgb   = out;
    float* out_alpha = out + BATCH*3;
    float* out_depth = out + BATCH*3 + (size_t)BATCH*NINTRS;

    unsigned short* ab = (unsigned short*)d_ws;   // 114688 B needed

    build_atomsB<<<28, 256, 0, stream>>>(atoms, ab);
    shdict_fused<<<BATCH/2, 256, 0, stream>>>(q, ab, ipts, intr, raysd,
                                              out_rgb, out_alpha, out_depth);
}

// Round 11
// 58.387 us; speedup vs baseline: 1.2986x; 1.0144x over previous
//
#include <hip/hip_runtime.h>
#include <hip/hip_bf16.h>
#include <math.h>

#define BATCH   2048
#define NINTRS  256
#define VALID   128
#define NATOMS  256
#define DDIM    28   // 3*9+1

typedef float  f32x4  __attribute__((ext_vector_type(4)));
typedef short  bf16x8 __attribute__((ext_vector_type(8)));

__device__ __forceinline__ unsigned short f32_to_bf16(float f) {
    unsigned int u = __float_as_uint(f);
    u = (u + 0x7FFFu + ((u >> 16) & 1u)) >> 16;   // RNE
    return (unsigned short)u;
}

// ---------------------------------------------------------------------------
// Pre-pass: ab[d][a] = 16B chunk {bf16 atoms[a][d][c], c=0..7}. 112 KB.
// Thread t -> (a = t/28, d = t%28): source address (a*28+d)*8 floats == t*8
// -> consecutive lanes read consecutive 32 B: perfectly coalesced reads.
// Writes scatter (stride 4 KB) but stores don't stall the pipeline.
// ---------------------------------------------------------------------------
__global__ __launch_bounds__(256)
void build_atomsB(const float* __restrict__ atoms, unsigned short* __restrict__ ab)
{
    const int t = blockIdx.x * 256 + threadIdx.x;   // 0..7167
    const int a = t / 28;
    const int d = t - a * 28;
    const float* src = atoms + (size_t)t * 8;       // contiguous per lane
    f32x4 v0 = *(const f32x4*)(src);
    f32x4 v1 = *(const f32x4*)(src + 4);
    bf16x8 o;
    #pragma unroll
    for (int j = 0; j < 4; ++j) {
        o[j]   = (short)f32_to_bf16(v0[j]);
        o[j+4] = (short)f32_to_bf16(v1[j]);
    }
    *(bf16x8*)(ab + ((size_t)(d * 256 + a)) * 8) = o;
}

// ---------------------------------------------------------------------------
// Main: one block per ray (R8 structure, depth-5 q prefetch).
//   phase B: ab -> Bs[32 col][256 a] bf16 in LDS, two 14-chunk halves (56 VGPR).
//   K-loop:  C[pt,col] = sum_a q[pt,a]*Bs[col,a] via MFMA. A-operands
//            prefetched straight from global q into registers via inline-asm
//            global_load_dwordx4 (un-sinkable), DEPTH-5, counted vmcnt +
//            sched_barrier(0) (rule #18). LDS = 23 KB; 4 blocks/CU.
//   epilogue: trilinear-weight c-reduction + transmittance scan (wave 0).
// ---------------------------------------------------------------------------
__global__ __launch_bounds__(256, 4)
void shdict_fused(const float* __restrict__ q,      // [BATCH*VALID][256]
                  const unsigned short* __restrict__ ab,  // [28][256] bf16x8
                  const float* __restrict__ ipts,   // [BATCH*VALID][3]
                  const float* __restrict__ intr,   // [BATCH][257]
                  const float* __restrict__ raysd,  // [BATCH][3]
                  float* __restrict__ out_rgb,      // [BATCH][3]
                  float* __restrict__ out_alpha,    // [BATCH][256]
                  float* __restrict__ out_depth)    // [BATCH]
{
    __shared__ char  bs[32 * 256 * 2];      // 16 KB Bs[col][a] bf16, XOR-swizzled
    __shared__ float w_lds[VALID][9];       // trilinear weights (+1 pad)
    __shared__ float pr_lds[VALID][5];      // rgb0,rgb1,rgb2,sigma (+1 pad)

    const int ray  = blockIdx.x;
    const int tid  = threadIdx.x;
    const int lane = tid & 63;
    const int wav  = tid >> 6;

    // ---- scalar input loads; consumed immediately below ----
    const float rdx = raysd[ray*3+0], rdy = raysd[ray*3+1], rdz = raysd[ray*3+2];
    float px = 0.f, py = 0.f, pz = 0.f;
    if (tid < VALID) {
        const int n = ray * VALID + tid;
        px = ipts[n*3+0]*128.0f + 1e-5f;
        py = ipts[n*3+1]*128.0f + 1e-5f;
        pz = ipts[n*3+2]*128.0f + 1e-5f;
    }

    // ---- SH basis ----
    const float ss = rdx*rdx + rdy*rdy + rdz*rdz;
    const float rn = rsqrtf(ss);
    const float x = rdx*rn, y = rdy*rn, z = rdz*rn;
    float sh[9];
    sh[0] = 0.28209479177387814f;
    sh[1] = -0.4886025119029199f * y;
    sh[2] =  0.4886025119029199f * z;
    sh[3] = -0.4886025119029199f * x;
    sh[4] =  1.0925484305920792f * x * y;
    sh[5] = -1.0925484305920792f * y * z;
    sh[6] =  0.31539156525252005f * (2.0f*z*z - x*x - y*y);
    sh[7] = -1.0925484305920792f * x * z;
    sh[8] =  0.5462742152960396f * (x-y)*(x+y);

    // ---- phase A: trilinear weights (consumes px/py/pz early) ----
    if (tid < VALID) {
        const float fx = px - floorf(px);
        const float fy = py - floorf(py);
        const float fz = pz - floorf(pz);
        #pragma unroll
        for (int c = 0; c < 8; ++c) {
            const float wx = (c & 4) ? fx : 1.0f - fx;
            const float wy = (c & 2) ? fy : 1.0f - fy;
            const float wz = (c & 1) ? fz : 1.0f - fz;
            w_lds[tid][c] = wx * wy * wz;
        }
    }

    // ---- phase B: contract ab -> Bs[col = kp*8+c][a = tid], two halves ----
    {
        const int a = tid;
        float accB[3][8];
        #pragma unroll
        for (int k = 0; k < 3; ++k)
            #pragma unroll
            for (int c = 0; c < 8; ++c) accB[k][c] = 0.0f;

        bf16x8 h[14];
        // half 1: d = 0..13
        #pragma unroll
        for (int d = 0; d < 14; ++d)
            h[d] = *(const bf16x8*)(ab + ((size_t)(d * 256 + a)) * 8);
        #pragma unroll
        for (int d = 0; d < 14; ++d) {
            const int kp = d / 9, j = d - kp * 9;
            const float s = sh[j];
            const unsigned int* u = (const unsigned int*)&h[d];
            #pragma unroll
            for (int i = 0; i < 4; ++i) {
                const float flo = __uint_as_float(u[i] << 16);
                const float fhi = __uint_as_float(u[i] & 0xffff0000u);
                accB[kp][2*i]   = fmaf(s, flo, accB[kp][2*i]);
                accB[kp][2*i+1] = fmaf(s, fhi, accB[kp][2*i+1]);
            }
        }
        __builtin_amdgcn_sched_barrier(0);   // don't hoist half-2 loads above
        // half 2: d = 14..27 (d=27 is sigma, kept raw in h[13])
        #pragma unroll
        for (int d = 0; d < 14; ++d)
            h[d] = *(const bf16x8*)(ab + ((size_t)((d + 14) * 256 + a)) * 8);
        #pragma unroll
        for (int d = 0; d < 13; ++d) {
            const int dd = d + 14;
            const int kp = dd / 9, j = dd - kp * 9;
            const float s = sh[j];
            const unsigned int* u = (const unsigned int*)&h[d];
            #pragma unroll
            for (int i = 0; i < 4; ++i) {
                const float flo = __uint_as_float(u[i] << 16);
                const float fhi = __uint_as_float(u[i] & 0xffff0000u);
                accB[kp][2*i]   = fmaf(s, flo, accB[kp][2*i]);
                accB[kp][2*i+1] = fmaf(s, fhi, accB[kp][2*i+1]);
            }
        }
        #pragma unroll
        for (int kp = 0; kp < 3; ++kp)
            #pragma unroll
            for (int c = 0; c < 8; ++c) {
                const int col = kp*8 + c;
                unsigned byte = ((unsigned)col << 9) + ((unsigned)a << 1);
                byte ^= (unsigned)((col & 7) << 4);
                *(unsigned short*)(bs + byte) = f32_to_bf16(accB[kp][c]);
            }
        const unsigned short* sv = (const unsigned short*)&h[13];
        #pragma unroll
        for (int c = 0; c < 8; ++c) {
            const int col = 24 + c;
            unsigned byte = ((unsigned)col << 9) + ((unsigned)a << 1);
            byte ^= (unsigned)((col & 7) << 4);
            *(unsigned short*)(bs + byte) = sv[c];
        }
    }

    // ---- register prefetch pipeline for A-fragments, depth 5 ----
    // Lane l covers rows (l&15) and (l&15)+16, k = (l>>4)*8 + 0..7 per step.
    const int row  = lane & 15;
    const int kgrp = lane >> 4;
    const float* ga0 = q + (size_t)(ray*VALID + wav*32 + row) * NATOMS + kgrp*8;
    const float* ga1 = ga0 + 16 * NATOMS;

    f32x4 pf[5][4];

#define ISSUE_STEP(s, kk) do {                                                   \
    const float* _p0 = ga0 + (kk)*32;                                            \
    const float* _p1 = ga1 + (kk)*32;                                            \
    asm volatile("global_load_dwordx4 %0, %1, off" : "=v"(pf[s][0]) : "v"(_p0)   : "memory"); \
    asm volatile("global_load_dwordx4 %0, %1, off" : "=v"(pf[s][1]) : "v"(_p0+4) : "memory"); \
    asm volatile("global_load_dwordx4 %0, %1, off" : "=v"(pf[s][2]) : "v"(_p1)   : "memory"); \
    asm volatile("global_load_dwordx4 %0, %1, off" : "=v"(pf[s][3]) : "v"(_p1+4) : "memory"); \
} while (0)

    // All compiler VMEM (raysd/ipts/ab halves) fully consumed above -> vmcnt==0.
    asm volatile("s_waitcnt vmcnt(0)" ::: "memory");
    ISSUE_STEP(0, 0);
    ISSUE_STEP(1, 1);
    ISSUE_STEP(2, 2);
    ISSUE_STEP(3, 3);
    ISSUE_STEP(4, 4);

    // bs/w_lds visibility: lgkmcnt drain + raw barrier (no vmcnt drain).
    asm volatile("s_waitcnt lgkmcnt(0)" ::: "memory");
    __builtin_amdgcn_s_barrier();

    // ---- K-loop: 8 steps of K=32, depth-5 register pipeline ----
    f32x4 acc[2][2];
    #pragma unroll
    for (int m = 0; m < 2; ++m)
        #pragma unroll
        for (int n = 0; n < 2; ++n)
            acc[m][n] = (f32x4){0.f, 0.f, 0.f, 0.f};

    #pragma unroll
    for (int ks = 0; ks < 8; ++ks) {
        // wait for step ks's 4 loads; N = 4*(min(5, 8-ks) - 1)
        if (ks <= 3)      asm volatile("s_waitcnt vmcnt(16)" ::: "memory");
        else if (ks == 4) asm volatile("s_waitcnt vmcnt(12)" ::: "memory");
        else if (ks == 5) asm volatile("s_waitcnt vmcnt(8)"  ::: "memory");
        else if (ks == 6) asm volatile("s_waitcnt vmcnt(4)"  ::: "memory");
        else              asm volatile("s_waitcnt vmcnt(0)"  ::: "memory");
        __builtin_amdgcn_sched_barrier(0);   // rule #18: pin consumers below

        const int s = ks % 5;
        bf16x8 af0, af1;
        #pragma unroll
        for (int j = 0; j < 4; ++j) {
            af0[j]   = (short)f32_to_bf16(pf[s][0][j]);
            af0[j+4] = (short)f32_to_bf16(pf[s][1][j]);
            af1[j]   = (short)f32_to_bf16(pf[s][2][j]);
            af1[j+4] = (short)f32_to_bf16(pf[s][3][j]);
        }

        // reissue this slot for step ks+5 (after consumption)
        if (ks + 5 < 8) ISSUE_STEP(s, ks + 5);

        bf16x8 bfrag[2];
        const int abase = ks*32 + kgrp*8;
        #pragma unroll
        for (int nt = 0; nt < 2; ++nt) {
            const int col = nt*16 + row;
            unsigned byte = ((unsigned)col << 9) + ((unsigned)abase << 1);
            byte ^= (unsigned)((col & 7) << 4);
            bfrag[nt] = *(const bf16x8*)(bs + byte);
        }

        acc[0][0] = __builtin_amdgcn_mfma_f32_16x16x32_bf16(af0, bfrag[0], acc[0][0], 0, 0, 0);
        acc[0][1] = __builtin_amdgcn_mfma_f32_16x16x32_bf16(af0, bfrag[1], acc[0][1], 0, 0, 0);
        acc[1][0] = __builtin_amdgcn_mfma_f32_16x16x32_bf16(af1, bfrag[0], acc[1][0], 0, 0, 0);
        acc[1][1] = __builtin_amdgcn_mfma_f32_16x16x32_bf16(af1, bfrag[1], acc[1][1], 0, 0, 0);
    }
#undef ISSUE_STEP

    // ---- Epilogue: out[pt,kp] = sum_c w[pt,c] * C[pt, kp*8+c] ----
    // D layout: lane holds D[(lane>>4)*4 + r][lane&15]; col = kph*8 + cc.
    const int cc  = lane & 7;
    const int kph = (lane & 15) >> 3;
    #pragma unroll
    for (int m = 0; m < 2; ++m) {
        const int ptb = wav*32 + m*16 + kgrp*4;
        #pragma unroll
        for (int nt = 0; nt < 2; ++nt) {
            const int kp = nt*2 + kph;
            #pragma unroll
            for (int r = 0; r < 4; ++r) {
                float t = acc[m][nt][r] * w_lds[ptb + r][cc];
                t += __shfl_xor(t, 1);
                t += __shfl_xor(t, 2);
                t += __shfl_xor(t, 4);
                if (cc == 0) pr_lds[ptb + r][kp] = t;
            }
        }
    }
    __syncthreads();

    // ---- Render scan (wave 0): 2 samples per lane ----
    if (wav == 0) {
        const float rnorm = sqrtf(ss);
        const int i0 = lane * 2;
        const float t0 = intr[ray*257 + i0];
        const float t1 = intr[ray*257 + i0 + 1];
        const float t2 = intr[ray*257 + i0 + 2];
        const float d0 = (t1 - t0) * rnorm;
        const float d1 = (t2 - t1) * rnorm;
        const float s0 = fmaxf(pr_lds[i0][3],     0.0f);
        const float s1 = fmaxf(pr_lds[i0 + 1][3], 0.0f);
        const float a0 = 1.0f - __expf(-s0 * d0);
        const float a1 = 1.0f - __expf(-s1 * d1);
        const float f0 = 1.0f - a0 + 1e-10f;
        const float f1 = 1.0f - a1 + 1e-10f;

        float pprod = f0 * f1;
        #pragma unroll
        for (int off = 1; off < 64; off <<= 1) {
            float v = __shfl_up(pprod, off);
            if (lane >= off) pprod *= v;
        }
        float excl = __shfl_up(pprod, 1);
        if (lane == 0) excl = 1.0f;

        const float tr0 = excl;
        const float tr1 = excl * f0;
        const float al0 = a0 * tr0;
        const float al1 = a1 * tr1;
        const float mid0 = 0.5f * (t0 + t1);
        const float mid1 = 0.5f * (t1 + t2);

        const float r0 = 1.0f / (1.0f + __expf(-pr_lds[i0][0]));
        const float g0 = 1.0f / (1.0f + __expf(-pr_lds[i0][1]));
        const float b0 = 1.0f / (1.0f + __expf(-pr_lds[i0][2]));
        const float r1 = 1.0f / (1.0f + __expf(-pr_lds[i0 + 1][0]));
        const float g1 = 1.0f / (1.0f + __expf(-pr_lds[i0 + 1][1]));
        const float b1 = 1.0f / (1.0f + __expf(-pr_lds[i0 + 1][2]));

        float sum_r = al0*r0 + al1*r1;
        float sum_g = al0*g0 + al1*g1;
        float sum_b = al0*b0 + al1*b1;
        float sum_d = al0*mid0 + al1*mid1;
        float sum_a = al0 + al1;
        #pragma unroll
        for (int off = 1; off < 64; off <<= 1) {
            sum_r += __shfl_xor(sum_r, off);
            sum_g += __shfl_xor(sum_g, off);
            sum_b += __shfl_xor(sum_b, off);
            sum_d += __shfl_xor(sum_d, off);
            sum_a += __shfl_xor(sum_a, off);
        }
        if (lane == 0) {
            const float bkgd = 1.0f - sum_a;
            out_rgb[ray*3 + 0] = sum_r + bkgd;
            out_rgb[ray*3 + 1] = sum_g + bkgd;
            out_rgb[ray*3 + 2] = sum_b + bkgd;
            out_depth[ray]     = sum_d;
        }
        float2 av; av.x = a0; av.y = a1;
        *(float2*)(out_alpha + (size_t)ray*NINTRS + i0) = av;
        float2 zz; zz.x = 0.0f; zz.y = 0.0f;
        *(float2*)(out_alpha + (size_t)ray*NINTRS + VALID + i0) = zz;
    }
}

extern "C" void kernel_launch(void* const* d_in, const int* in_sizes, int n_in,
                              void* d_out, int out_size, void* d_ws, size_t ws_size,
                              hipStream_t stream)
{
    const float* q     = (const float*)d_in[0];
    const float* atoms = (const float*)d_in[1];
    const float* ipts  = (const float*)d_in[2];
    const float* intr  = (const float*)d_in[3];
    const float* raysd = (const float*)d_in[4];
    // d_in[5] (flat_idx) is b*NINTRS+i by construction; derived analytically.

    float* out = (float*)d_out;
    float* out_rgb   = out;
    float* out_alpha = out + BATCH*3;
    float* out_depth = out + BATCH*3 + (size_t)BATCH*NINTRS;

    unsigned short* ab = (unsigned short*)d_ws;   // 114688 B needed

    build_atomsB<<<28, 256, 0, stream>>>(atoms, ab);
    shdict_fused<<<BATCH, 256, 0, stream>>>(q, ab, ipts, intr, raysd,
                                            out_rgb, out_alpha, out_depth);
}